// Round 21
// baseline (50.841 us; speedup 1.0000x reference)
//
#include <hip/hip_runtime.h>
#include <hip/hip_fp16.h>

#define NG 14
#define NE 16
#define NW 32            // wafers per chunk
#define YW 152           // per-wafer y stride in halfs

typedef __fp16 h2 __attribute__((ext_vector_type(2)));
typedef __fp16 h4 __attribute__((ext_vector_type(4)));
typedef __fp16 h8 __attribute__((ext_vector_type(8)));

__device__ __forceinline__ float hdot4(h4 a, h4 b, float c) {
    const h2 a0 = __builtin_shufflevector(a, a, 0, 1);
    const h2 a1 = __builtin_shufflevector(a, a, 2, 3);
    const h2 b0 = __builtin_shufflevector(b, b, 0, 1);
    const h2 b1 = __builtin_shufflevector(b, b, 2, 3);
    return __builtin_amdgcn_fdot2(a1, b1, __builtin_amdgcn_fdot2(a0, b0, c, false), false);
}

// serial one-block bin (r16's proven version)
__global__ __launch_bounds__(1024) void bin_kernel(const int* __restrict__ keys, int N,
                                                   int NBW, int* __restrict__ sorted) {
    __shared__ int hist[NE], offs[NE], cur[NE];
    __shared__ int runTot;
    const int t = threadIdx.x;
    if (t < NE) { hist[t] = 0; cur[t] = 0; }
    __syncthreads();
    for (int i = t; i < N; i += 1024) atomicAdd(&hist[keys[i]], 1);
    __syncthreads();
    if (t == 0) {
        int run = 0;
        for (int e = 0; e < NE; ++e) { offs[e] = run; run += (hist[e] + NW - 1) & ~(NW - 1); }
        runTot = run;
    }
    __syncthreads();
    for (int i = t; i < N; i += 1024) {
        const int e = keys[i];
        sorted[offs[e] + atomicAdd(&cur[e], 1)] = i;
    }
    {   // pad fill
        const int e = t >> 6, l = t & 63;
        const int cnt = hist[e];
        const int padded = (cnt + NW - 1) & ~(NW - 1);
        if (l < padded - cnt) sorted[offs[e] + cnt + l] = -1;
    }
    for (int i = runTot + t; i < NBW; i += 1024) sorted[i] = -1;
}

// load one image row into a zero-padded [10] register array
#define LOADROW(dst, R) do {                                  \
    const float4 a_ = *(const float4*)(xg + (R) * 8);         \
    const float4 b_ = *(const float4*)(xg + (R) * 8 + 4);     \
    dst[0]=0.f; dst[9]=0.f;                                   \
    dst[1]=a_.x; dst[2]=a_.y; dst[3]=a_.z; dst[4]=a_.w;       \
    dst[5]=b_.x; dst[6]=b_.y; dst[7]=b_.z; dst[8]=b_.w;       \
} while (0)

// conv rows 2pr,2pr+1 + pool + GEMV(pr)
#define CONVGEMV(PR, RM, R0_, R1_, R2_, TZ, BZ)                                \
    {                                                                          \
        float res[4];                                                          \
        _Pragma("unroll")                                                      \
        for (int pc = 0; pc < 4; ++pc) {                                       \
            float mx = 0.f;                                                    \
            _Pragma("unroll")                                                  \
            for (int cl = 0; cl < 2; ++cl) {                                   \
                const int c = 2 * pc + cl;                                     \
                float s0 = w3*R0_[c] + w4*R0_[c+1] + w5*R0_[c+2]               \
                         + w7*R1_[c+1] + w8*R1_[c+2];                          \
                if (!(TZ)) s0 += w0*RM[c] + w1*RM[c+1];                        \
                float s1 = w0*R0_[c] + w1*R0_[c+1]                             \
                         + w3*R1_[c] + w4*R1_[c+1] + w5*R1_[c+2];              \
                if (!(BZ)) s1 += w7*R2_[c+1] + w8*R2_[c+2];                    \
                mx = fmaxf(mx, fmaxf(s0, s1));                                 \
            }                                                                  \
            res[pc] = mx;                                                      \
        }                                                                      \
        const h2 ra = __builtin_amdgcn_cvt_pkrtz(res[0], res[1]);              \
        const h2 rb = __builtin_amdgcn_cvt_pkrtz(res[2], res[3]);              \
        const h2* eb2 = &ews2[((PR) * 8 + ch) * 20];                           \
        _Pragma("unroll")                                                      \
        for (int q = 0; q < 4; ++q) {                                          \
            const h8 v = *(const h8*)(eb2 + q * 4);                            \
            const h2 a0 = __builtin_shufflevector(v, v, 0, 1);                 \
            const h2 a1 = __builtin_shufflevector(v, v, 2, 3);                 \
            const h2 b0 = __builtin_shufflevector(v, v, 4, 5);                 \
            const h2 b1 = __builtin_shufflevector(v, v, 6, 7);                 \
            part[2*q]   = __builtin_amdgcn_fdot2(rb, a1,                       \
                          __builtin_amdgcn_fdot2(ra, a0, part[2*q],   false), false); \
            part[2*q+1] = __builtin_amdgcn_fdot2(rb, b1,                       \
                          __builtin_amdgcn_fdot2(ra, b0, part[2*q+1], false), false); \
        }                                                                      \
    }

__global__ __launch_bounds__(256, 6) void ae_main(
    const float* __restrict__ x,
    const int*   __restrict__ keys,
    const float* __restrict__ conv_mask,
    const float* __restrict__ enc_conv_w,
    const float* __restrict__ enc_dense_w,
    const float* __restrict__ enc_dense_b,
    const float* __restrict__ dec_dense_w,
    const float* __restrict__ dec_dense_b,
    const float* __restrict__ dec_tconv_w,
    const float* __restrict__ dec_tconv_b,
    const int*   __restrict__ sorted,
    const int    CHUNKS,
    float* __restrict__ out)
{
    const int t = threadIdx.x;
    const int pair = blockIdx.x / NG;
    const int g = blockIdx.x - pair * NG;

    __shared__ __attribute__((aligned(16))) __half yt[NW * YW]; // y in fp16 (9.5 KB)
    __shared__ __attribute__((aligned(16))) h2 ews2[640];       // enc w fp16
    __shared__ __attribute__((aligned(16))) h2 dws2[512];       // dec w fp16, XOR-swizzled
    __shared__ __attribute__((aligned(16))) h2 wtr2[48];        // tconv w fp16; taps 9..11 = 0
    __shared__ __attribute__((aligned(16))) float wcs[72];      // masked conv w [tap*8+ch]
    __shared__ float dbs[128];                                  // dec bias [p*8+ch]
    __shared__ float ebs[8];

    const int w = t >> 3, ch = t & 7;
    float rowA[10], rowB[10], rowC[10], rowD[10], rowE[10];
    int kcur = -1;

    for (int c2 = 0; c2 < 2; ++c2) {
        const int chunk = pair * 2 + c2;
        if (chunk >= CHUNKS) break;                 // block-uniform
        const int* chunkIds = sorted + chunk * NW;
        const int i0 = chunkIds[0];
        if (i0 < 0) break;                          // block-uniform
        const int k = keys[i0];

        const int idw = chunkIds[w];
        const int idr = (idw < 0) ? i0 : idw;
        const float* xg = x + (size_t)idr * 896 + g * 64;

        // early x loads (touch both 128B lines before staging / compute)
        LOADROW(rowA, 0);
        LOADROW(rowB, 1);
        LOADROW(rowC, 2);
        LOADROW(rowD, 4);

        if (k != kcur) {
            if (kcur >= 0) __syncthreads();        // all waves done reading old weights
            const size_t wg1024 = (size_t)(k * NG + g) * 1024;
            {   // ews: thread t <-> (o = t>>5, ch = (t>>2)&7, pr = t&3)
                const float4 w4_ = *(const float4*)(enc_dense_w + wg1024 + 4 * t);
                const int o = t >> 5, cc = (t >> 2) & 7, pr = t & 3;
                const int base = (pr * 8 + cc) * 20 + o * 2;
                ews2[base]     = __builtin_amdgcn_cvt_pkrtz(w4_.x, w4_.y);
                ews2[base + 1] = __builtin_amdgcn_cvt_pkrtz(w4_.z, w4_.w);
            }
            if (t < 128) {  // dws: f-row t -> swizzled row p*8 + (c ^ (p&7))
                const float4 a = *(const float4*)(dec_dense_w + wg1024 + 8 * t);
                const float4 b = *(const float4*)(dec_dense_w + wg1024 + 8 * t + 4);
                const int cc = t >> 4, p = t & 15;
                h2* dst = &dws2[(p * 8 + (cc ^ (p & 7))) * 4];
                dst[0] = __builtin_amdgcn_cvt_pkrtz(a.x, a.y);
                dst[1] = __builtin_amdgcn_cvt_pkrtz(a.z, a.w);
                dst[2] = __builtin_amdgcn_cvt_pkrtz(b.x, b.y);
                dst[3] = __builtin_amdgcn_cvt_pkrtz(b.z, b.w);
            } else if (t < 200) {
                const int i = t - 128, cc = i / 9, tap = i - cc * 9;
                wcs[tap * 8 + cc] = enc_conv_w[(size_t)k * 1008 + (g * 8 + cc) * 9 + tap] * conv_mask[tap];
            } else if (t < 208) {
                ebs[t - 200] = enc_dense_b[(size_t)k * 112 + g * 8 + (t - 200)];
            } else if (t < 256) {
                const int i = t - 208, tap = i >> 2, j = i & 3;
                h2 v = (h2)(__fp16)0.f;
                if (tap < 9) {
                    const float wa = dec_tconv_w[(size_t)k * 1008 + (g * 8 + 2*j) * 9 + tap];
                    const float wb = dec_tconv_w[(size_t)k * 1008 + (g * 8 + 2*j + 1) * 9 + tap];
                    v = __builtin_amdgcn_cvt_pkrtz(wa, wb);
                }
                wtr2[tap * 4 + j] = v;
            }
            if (t < 128) {
                dbs[(t & 15) * 8 + (t >> 4)] = dec_dense_b[(size_t)k * 1792 + g * 128 + t];
            }
            __syncthreads();
            kcur = k;
        }

        // ---- P1+P2 fused: fp32 conv (7 taps) + ReLU + maxpool -> enc GEMV (fdot2) ----
        const float w0 = wcs[0*8+ch], w1 = wcs[1*8+ch], w3 = wcs[3*8+ch], w4 = wcs[4*8+ch],
                    w5 = wcs[5*8+ch], w7 = wcs[7*8+ch], w8 = wcs[8*8+ch];
        float part[8] = {0.f,0.f,0.f,0.f,0.f,0.f,0.f,0.f};

        CONVGEMV(0, rowA, rowA, rowB, rowC, 1, 0);   // rows -1(zero),0,1,2
        LOADROW(rowE, 3);
        CONVGEMV(1, rowB, rowC, rowE, rowD, 0, 0);   // rows 1,2,3,4
        LOADROW(rowA, 5);
        LOADROW(rowB, 6);
        CONVGEMV(2, rowE, rowD, rowA, rowB, 0, 0);   // rows 3,4,5,6
        LOADROW(rowC, 7);
        CONVGEMV(3, rowA, rowB, rowC, rowC, 0, 1);   // rows 5,6,7,8(zero)

        // ---- reduce across the 8 channel lanes; z in registers ----
        float z[8];
        #pragma unroll
        for (int o = 0; o < 8; ++o) {
            float v = part[o];
            v += __shfl_xor(v, 1);
            v += __shfl_xor(v, 2);
            v += __shfl_xor(v, 4);
            z[o] = fmaxf(v + ebs[o], 0.f);
        }
        const h2 z01 = __builtin_amdgcn_cvt_pkrtz(z[0], z[1]);
        const h2 z23 = __builtin_amdgcn_cvt_pkrtz(z[2], z[3]);
        const h2 z45 = __builtin_amdgcn_cvt_pkrtz(z[4], z[5]);
        const h2 z67 = __builtin_amdgcn_cvt_pkrtz(z[6], z[7]);

        // ---- P3 (transposed): thread (w,ch) computes pixels p = ch, ch+8 ----
        __half* yw_ = yt + w * YW;
        #pragma unroll
        for (int pp = 0; pp < 2; ++pp) {
            const int p = ch + pp * 8;
            const int px = p & 7;
            const float4 db0 = *(const float4*)(dbs + p * 8);
            const float4 db1 = *(const float4*)(dbs + p * 8 + 4);
            const float dbv[8] = {db0.x, db0.y, db0.z, db0.w, db1.x, db1.y, db1.z, db1.w};
            __fp16 yv[8];
            #pragma unroll
            for (int c = 0; c < 8; ++c) {
                const h8 v = *(const h8*)(&dws2[(p * 8 + (c ^ px)) * 4]);
                const h2 v0 = __builtin_shufflevector(v, v, 0, 1);
                const h2 v1 = __builtin_shufflevector(v, v, 2, 3);
                const h2 v2 = __builtin_shufflevector(v, v, 4, 5);
                const h2 v3 = __builtin_shufflevector(v, v, 6, 7);
                float acc = dbv[c];
                acc = __builtin_amdgcn_fdot2(z01, v0, acc, false);
                acc = __builtin_amdgcn_fdot2(z23, v1, acc, false);
                acc = __builtin_amdgcn_fdot2(z45, v2, acc, false);
                acc = __builtin_amdgcn_fdot2(z67, v3, acc, false);
                yv[c ^ px] = (__fp16)fmaxf(acc, 0.f);
            }
            h8 o8;
            #pragma unroll
            for (int c = 0; c < 8; ++c) o8[c] = yv[c ^ px];
            *(h8*)(yw_ + (p >> 2) * 40 + (p & 3) * 8) = o8;
        }
        // P4 reads only this wave's own y rows: drain LDS writes, no block barrier.
        asm volatile("s_waitcnt lgkmcnt(0)" ::: "memory");

        // ---- P4: ConvTranspose2d via fp16 fdot2; thread (w, oi=ch) -> one out row ----
        const int oi = ch;
        int iA, rA, iB, rB;
        if ((oi & 1) == 0) { iA = oi >> 1; rA = 3; iB = 0; rB = 9; }
        else { iA = (oi - 1) >> 1; rA = 6;
               if (oi < 7) { iB = (oi + 1) >> 1; rB = 0; } else { iB = 0; rB = 9; } }
        const float bias = dec_tconv_b[k * NG + g];
        const __fp16* ywh = (const __fp16*)(yt) + w * YW;

        h8 yAv[4], yBv[4];
        #pragma unroll
        for (int j = 0; j < 4; ++j) {
            yAv[j] = *(const h8*)(ywh + iA * 40 + j * 8);
            yBv[j] = *(const h8*)(ywh + iB * 40 + j * 8);
        }
        float acc[8] = {0.f,0.f,0.f,0.f,0.f,0.f,0.f,0.f};
        #pragma unroll
        for (int hc = 0; hc < 2; ++hc) {
            const h4 wA0 = *(const h4*)(wtr2 + (rA + 0) * 4 + hc * 2);
            const h4 wA1 = *(const h4*)(wtr2 + (rA + 1) * 4 + hc * 2);
            const h4 wA2 = *(const h4*)(wtr2 + (rA + 2) * 4 + hc * 2);
            const h4 wB0 = *(const h4*)(wtr2 + (rB + 0) * 4 + hc * 2);
            const h4 wB1 = *(const h4*)(wtr2 + (rB + 1) * 4 + hc * 2);
            const h4 wB2 = *(const h4*)(wtr2 + (rB + 2) * 4 + hc * 2);
            h4 yA[4], yB[4];
            #pragma unroll
            for (int j = 0; j < 4; ++j) {
                yA[j] = hc ? __builtin_shufflevector(yAv[j], yAv[j], 4, 5, 6, 7)
                           : __builtin_shufflevector(yAv[j], yAv[j], 0, 1, 2, 3);
                yB[j] = hc ? __builtin_shufflevector(yBv[j], yBv[j], 4, 5, 6, 7)
                           : __builtin_shufflevector(yBv[j], yBv[j], 0, 1, 2, 3);
            }
            acc[0] = hdot4(wB1, yB[0], hdot4(wA1, yA[0], acc[0]));
            acc[1] = hdot4(wB0, yB[1], hdot4(wB2, yB[0],
                     hdot4(wA0, yA[1], hdot4(wA2, yA[0], acc[1]))));
            acc[2] = hdot4(wB1, yB[1], hdot4(wA1, yA[1], acc[2]));
            acc[3] = hdot4(wB0, yB[2], hdot4(wB2, yB[1],
                     hdot4(wA0, yA[2], hdot4(wA2, yA[1], acc[3]))));
            acc[4] = hdot4(wB1, yB[2], hdot4(wA1, yA[2], acc[4]));
            acc[5] = hdot4(wB0, yB[3], hdot4(wB2, yB[2],
                     hdot4(wA0, yA[3], hdot4(wA2, yA[2], acc[5]))));
            acc[6] = hdot4(wB1, yB[3], hdot4(wA1, yA[3], acc[6]));
            acc[7] = hdot4(wB2, yB[3], hdot4(wA2, yA[3], acc[7]));
        }
        if (idw >= 0) {
            float* og = out + (size_t)idw * 896 + g * 64 + oi * 8;
            *(float4*)(og)     = make_float4(fmaxf(acc[0]+bias,0.f), fmaxf(acc[1]+bias,0.f),
                                             fmaxf(acc[2]+bias,0.f), fmaxf(acc[3]+bias,0.f));
            *(float4*)(og + 4) = make_float4(fmaxf(acc[4]+bias,0.f), fmaxf(acc[5]+bias,0.f),
                                             fmaxf(acc[6]+bias,0.f), fmaxf(acc[7]+bias,0.f));
        }
    }
}

extern "C" void kernel_launch(void* const* d_in, const int* in_sizes, int n_in,
                              void* d_out, int out_size, void* d_ws, size_t ws_size,
                              hipStream_t stream) {
    const float* x            = (const float*)d_in[0];
    const int*   keys         = (const int*)d_in[1];
    const float* conv_mask    = (const float*)d_in[2];
    const float* enc_conv_w   = (const float*)d_in[3];
    const float* enc_dense_w  = (const float*)d_in[4];
    const float* enc_dense_b  = (const float*)d_in[5];
    const float* dec_dense_w  = (const float*)d_in[6];
    const float* dec_dense_b  = (const float*)d_in[7];
    const float* dec_tconv_w  = (const float*)d_in[8];
    const float* dec_tconv_b  = (const float*)d_in[9];
    float* out = (float*)d_out;

    const int N = in_sizes[0] / (NG * 64);                   // 4096
    const int CHUNKS = (N + NE * (NW - 1)) / NW + 1;         // 144
    const int NPAIRS = (CHUNKS + 1) / 2;                     // 72
    int* sorted = (int*)d_ws;

    bin_kernel<<<1, 1024, 0, stream>>>(keys, N, CHUNKS * NW, sorted);
    ae_main<<<NPAIRS * NG, 256, 0, stream>>>(
        x, keys, conv_mask, enc_conv_w, enc_dense_w, enc_dense_b,
        dec_dense_w, dec_dense_b, dec_tconv_w, dec_tconv_b, sorted, CHUNKS, out);
}

// Round 22
// 26.841 us; speedup vs baseline: 1.8942x; 1.8942x over previous
//
#include <hip/hip_runtime.h>
#include <hip/hip_fp16.h>

#define NG 14
#define NE 16
#define NW 32            // wafers per chunk/block
#define YW 152           // per-wafer y stride in halfs

typedef __fp16 h2 __attribute__((ext_vector_type(2)));
typedef __fp16 h4 __attribute__((ext_vector_type(4)));
typedef __fp16 h8 __attribute__((ext_vector_type(8)));

__device__ __forceinline__ float hdot4(h4 a, h4 b, float c) {
    const h2 a0 = __builtin_shufflevector(a, a, 0, 1);
    const h2 a1 = __builtin_shufflevector(a, a, 2, 3);
    const h2 b0 = __builtin_shufflevector(b, b, 0, 1);
    const h2 b1 = __builtin_shufflevector(b, b, 2, 3);
    return __builtin_amdgcn_fdot2(a1, b1, __builtin_amdgcn_fdot2(a0, b0, c, false), false);
}

// serial one-block bin (proven fastest variant: r16/r18/r20)
__global__ __launch_bounds__(1024) void bin_kernel(const int* __restrict__ keys, int N,
                                                   int NBW, int* __restrict__ sorted) {
    __shared__ int hist[NE], offs[NE], cur[NE];
    __shared__ int runTot;
    const int t = threadIdx.x;
    if (t < NE) { hist[t] = 0; cur[t] = 0; }
    __syncthreads();
    for (int i = t; i < N; i += 1024) atomicAdd(&hist[keys[i]], 1);
    __syncthreads();
    if (t == 0) {
        int run = 0;
        for (int e = 0; e < NE; ++e) { offs[e] = run; run += (hist[e] + NW - 1) & ~(NW - 1); }
        runTot = run;
    }
    __syncthreads();
    for (int i = t; i < N; i += 1024) {
        const int e = keys[i];
        sorted[offs[e] + atomicAdd(&cur[e], 1)] = i;
    }
    {   // pad fill
        const int e = t >> 6, l = t & 63;
        const int cnt = hist[e];
        const int padded = (cnt + NW - 1) & ~(NW - 1);
        if (l < padded - cnt) sorted[offs[e] + cnt + l] = -1;
    }
    for (int i = runTot + t; i < NBW; i += 1024) sorted[i] = -1;
}

// load one image row into a zero-padded [10] register array
#define LOADROW(dst, R) do {                                  \
    const float4 a_ = *(const float4*)(xg + (R) * 8);         \
    const float4 b_ = *(const float4*)(xg + (R) * 8 + 4);     \
    dst[0]=0.f; dst[9]=0.f;                                   \
    dst[1]=a_.x; dst[2]=a_.y; dst[3]=a_.z; dst[4]=a_.w;       \
    dst[5]=b_.x; dst[6]=b_.y; dst[7]=b_.z; dst[8]=b_.w;       \
} while (0)

// conv rows 2pr,2pr+1 (rows RM,R0_,R1_,R2_ = img rows 2pr-1..2pr+2) + pool + GEMV(pr)
#define CONVGEMV(PR, RM, R0_, R1_, R2_, TZ, BZ)                                \
    {                                                                          \
        float res[4];                                                          \
        _Pragma("unroll")                                                      \
        for (int pc = 0; pc < 4; ++pc) {                                       \
            float mx = 0.f;                                                    \
            _Pragma("unroll")                                                  \
            for (int cl = 0; cl < 2; ++cl) {                                   \
                const int c = 2 * pc + cl;                                     \
                float s0 = w3*R0_[c] + w4*R0_[c+1] + w5*R0_[c+2]               \
                         + w7*R1_[c+1] + w8*R1_[c+2];                          \
                if (!(TZ)) s0 += w0*RM[c] + w1*RM[c+1];                        \
                float s1 = w0*R0_[c] + w1*R0_[c+1]                             \
                         + w3*R1_[c] + w4*R1_[c+1] + w5*R1_[c+2];              \
                if (!(BZ)) s1 += w7*R2_[c+1] + w8*R2_[c+2];                    \
                mx = fmaxf(mx, fmaxf(s0, s1));                                 \
            }                                                                  \
            res[pc] = mx;                                                      \
        }                                                                      \
        const h2 ra = __builtin_amdgcn_cvt_pkrtz(res[0], res[1]);              \
        const h2 rb = __builtin_amdgcn_cvt_pkrtz(res[2], res[3]);              \
        const h2* eb2 = &ews2[((PR) * 8 + ch) * 20];                           \
        _Pragma("unroll")                                                      \
        for (int q = 0; q < 4; ++q) {                                          \
            const h8 v = *(const h8*)(eb2 + q * 4);                            \
            const h2 a0 = __builtin_shufflevector(v, v, 0, 1);                 \
            const h2 a1 = __builtin_shufflevector(v, v, 2, 3);                 \
            const h2 b0 = __builtin_shufflevector(v, v, 4, 5);                 \
            const h2 b1 = __builtin_shufflevector(v, v, 6, 7);                 \
            part[2*q]   = __builtin_amdgcn_fdot2(rb, a1,                       \
                          __builtin_amdgcn_fdot2(ra, a0, part[2*q],   false), false); \
            part[2*q+1] = __builtin_amdgcn_fdot2(rb, b1,                       \
                          __builtin_amdgcn_fdot2(ra, b0, part[2*q+1], false), false); \
        }                                                                      \
    }

__global__ __launch_bounds__(256, 6) void ae_main(
    const float* __restrict__ x,
    const int*   __restrict__ keys,
    const float* __restrict__ conv_mask,
    const float* __restrict__ enc_conv_w,
    const float* __restrict__ enc_dense_w,
    const float* __restrict__ enc_dense_b,
    const float* __restrict__ dec_dense_w,
    const float* __restrict__ dec_dense_b,
    const float* __restrict__ dec_tconv_w,
    const float* __restrict__ dec_tconv_b,
    const int*   __restrict__ sorted,
    float* __restrict__ out)
{
    const int t = threadIdx.x;
    const int chunk = blockIdx.x / NG;
    const int g = blockIdx.x - chunk * NG;

    __shared__ __attribute__((aligned(16))) __half yt[NW * YW]; // y in fp16 (9.5 KB)
    __shared__ __attribute__((aligned(16))) h2 ews2[640];       // enc w fp16, (pr*8+ch)*20 + o*2+jj
    __shared__ __attribute__((aligned(16))) h2 dws2[512];       // dec w fp16, XOR-swizzled rows
    __shared__ __attribute__((aligned(16))) h2 wtr2[48];        // tconv w fp16; taps 9..11 = 0
    __shared__ __attribute__((aligned(16))) float wcs[72];      // masked conv w [tap*8+ch]
    __shared__ float dbs[128];                                  // dec bias [p*8+ch]
    __shared__ float ebs[8];

    const int* chunkIds = sorted + chunk * NW;
    const int i0 = chunkIds[0];
    if (i0 < 0) return;
    const int k = keys[i0];

    const int w = t >> 3, ch = t & 7;
    const int idw = chunkIds[w];
    const int idr = (idw < 0) ? i0 : idw;

    // ---- early x loads: rows 0,1,2,4 (touch both 128B lines before staging) ----
    const float* xg = x + (size_t)idr * 896 + g * 64;
    float rowA[10], rowB[10], rowC[10], rowD[10], rowE[10];
    LOADROW(rowA, 0);
    LOADROW(rowB, 1);
    LOADROW(rowC, 2);
    LOADROW(rowD, 4);

    // ---- stage weights into LDS (coalesced), dense + tconv weights packed fp16 ----
    const size_t wg1024 = (size_t)(k * NG + g) * 1024;
    {   // ews: thread t <-> (o = t>>5, ch = (t>>2)&7, pr = t&3), 4 floats each
        const float4 w4_ = *(const float4*)(enc_dense_w + wg1024 + 4 * t);
        const int o = t >> 5, c2 = (t >> 2) & 7, pr = t & 3;
        const int base = (pr * 8 + c2) * 20 + o * 2;
        ews2[base]     = __builtin_amdgcn_cvt_pkrtz(w4_.x, w4_.y);
        ews2[base + 1] = __builtin_amdgcn_cvt_pkrtz(w4_.z, w4_.w);
    }
    if (t < 128) {  // dws: f-row t (c2 = t>>4, p = t&15) -> swizzled row p*8 + (c2 ^ (p&7))
        const float4 a = *(const float4*)(dec_dense_w + wg1024 + 8 * t);
        const float4 b = *(const float4*)(dec_dense_w + wg1024 + 8 * t + 4);
        const int c2 = t >> 4, p = t & 15;
        h2* dst = &dws2[(p * 8 + (c2 ^ (p & 7))) * 4];
        dst[0] = __builtin_amdgcn_cvt_pkrtz(a.x, a.y);
        dst[1] = __builtin_amdgcn_cvt_pkrtz(a.z, a.w);
        dst[2] = __builtin_amdgcn_cvt_pkrtz(b.x, b.y);
        dst[3] = __builtin_amdgcn_cvt_pkrtz(b.z, b.w);
    } else if (t < 200) {
        const int i = t - 128, c2 = i / 9, tap = i - c2 * 9;
        wcs[tap * 8 + c2] = enc_conv_w[(size_t)k * 1008 + (g * 8 + c2) * 9 + tap] * conv_mask[tap];
    } else if (t < 208) {
        ebs[t - 200] = enc_dense_b[(size_t)k * 112 + g * 8 + (t - 200)];
    } else if (t < 256) {
        const int i = t - 208, tap = i >> 2, j = i & 3;    // 48 threads: taps 0..11
        h2 v = (h2)(__fp16)0.f;
        if (tap < 9) {
            const float wa = dec_tconv_w[(size_t)k * 1008 + (g * 8 + 2*j) * 9 + tap];
            const float wb = dec_tconv_w[(size_t)k * 1008 + (g * 8 + 2*j + 1) * 9 + tap];
            v = __builtin_amdgcn_cvt_pkrtz(wa, wb);
        }
        wtr2[tap * 4 + j] = v;
    }
    if (t < 128) {
        dbs[(t & 15) * 8 + (t >> 4)] = dec_dense_b[(size_t)k * 1792 + g * 128 + t];
    }
    __syncthreads();

    // ---- P1+P2 fused: fp32 conv (7 taps) + ReLU + maxpool -> enc GEMV (fdot2) ----
    const float w0 = wcs[0*8+ch], w1 = wcs[1*8+ch], w3 = wcs[3*8+ch], w4 = wcs[4*8+ch],
                w5 = wcs[5*8+ch], w7 = wcs[7*8+ch], w8 = wcs[8*8+ch];
    float part[8] = {0.f,0.f,0.f,0.f,0.f,0.f,0.f,0.f};

    CONVGEMV(0, rowA, rowA, rowB, rowC, 1, 0);   // rows -1(zero),0,1,2
    LOADROW(rowE, 3);
    CONVGEMV(1, rowB, rowC, rowE, rowD, 0, 0);   // rows 1,2,3,4
    LOADROW(rowA, 5);
    LOADROW(rowB, 6);
    CONVGEMV(2, rowE, rowD, rowA, rowB, 0, 0);   // rows 3,4,5,6
    LOADROW(rowC, 7);
    CONVGEMV(3, rowA, rowB, rowC, rowC, 0, 1);   // rows 5,6,7,8(zero)

    // ---- reduce across the 8 channel lanes; z in registers ----
    float z[8];
    #pragma unroll
    for (int o = 0; o < 8; ++o) {
        float v = part[o];
        v += __shfl_xor(v, 1);
        v += __shfl_xor(v, 2);
        v += __shfl_xor(v, 4);
        z[o] = fmaxf(v + ebs[o], 0.f);
    }
    const h2 z01 = __builtin_amdgcn_cvt_pkrtz(z[0], z[1]);
    const h2 z23 = __builtin_amdgcn_cvt_pkrtz(z[2], z[3]);
    const h2 z45 = __builtin_amdgcn_cvt_pkrtz(z[4], z[5]);
    const h2 z67 = __builtin_amdgcn_cvt_pkrtz(z[6], z[7]);

    // ---- P3 (transposed): thread (w,ch) computes pixels p = ch, ch+8, ALL channels ----
    __half* yw_ = yt + w * YW;
    #pragma unroll
    for (int pp = 0; pp < 2; ++pp) {
        const int p = ch + pp * 8;
        const int px = p & 7;
        const float4 db0 = *(const float4*)(dbs + p * 8);
        const float4 db1 = *(const float4*)(dbs + p * 8 + 4);
        const float dbv[8] = {db0.x, db0.y, db0.z, db0.w, db1.x, db1.y, db1.z, db1.w};
        __fp16 yv[8];
        #pragma unroll
        for (int c = 0; c < 8; ++c) {
            const h8 v = *(const h8*)(&dws2[(p * 8 + (c ^ px)) * 4]);
            const h2 v0 = __builtin_shufflevector(v, v, 0, 1);
            const h2 v1 = __builtin_shufflevector(v, v, 2, 3);
            const h2 v2 = __builtin_shufflevector(v, v, 4, 5);
            const h2 v3 = __builtin_shufflevector(v, v, 6, 7);
            float acc = dbv[c];
            acc = __builtin_amdgcn_fdot2(z01, v0, acc, false);
            acc = __builtin_amdgcn_fdot2(z23, v1, acc, false);
            acc = __builtin_amdgcn_fdot2(z45, v2, acc, false);
            acc = __builtin_amdgcn_fdot2(z67, v3, acc, false);
            yv[c ^ px] = (__fp16)fmaxf(acc, 0.f);
        }
        h8 o8;
        #pragma unroll
        for (int c = 0; c < 8; ++c) o8[c] = yv[c ^ px];
        *(h8*)(yw_ + (p >> 2) * 40 + (p & 3) * 8) = o8;
    }
    // P4 reads only this wave's own y rows: drain LDS writes, no block barrier.
    asm volatile("s_waitcnt lgkmcnt(0)" ::: "memory");

    // ---- P4: ConvTranspose2d via fp16 fdot2; thread (w, oi=ch) -> one out row ----
    const int oi = ch;
    int iA, rA, iB, rB;
    if ((oi & 1) == 0) { iA = oi >> 1; rA = 3; iB = 0; rB = 9; }
    else { iA = (oi - 1) >> 1; rA = 6;
           if (oi < 7) { iB = (oi + 1) >> 1; rB = 0; } else { iB = 0; rB = 9; } }
    const float bias = dec_tconv_b[k * NG + g];
    const __fp16* ywh = (const __fp16*)(yt) + w * YW;

    h8 yAv[4], yBv[4];
    #pragma unroll
    for (int j = 0; j < 4; ++j) {
        yAv[j] = *(const h8*)(ywh + iA * 40 + j * 8);
        yBv[j] = *(const h8*)(ywh + iB * 40 + j * 8);
    }
    float acc[8] = {0.f,0.f,0.f,0.f,0.f,0.f,0.f,0.f};
    #pragma unroll
    for (int hc = 0; hc < 2; ++hc) {
        const h4 wA0 = *(const h4*)(wtr2 + (rA + 0) * 4 + hc * 2);
        const h4 wA1 = *(const h4*)(wtr2 + (rA + 1) * 4 + hc * 2);
        const h4 wA2 = *(const h4*)(wtr2 + (rA + 2) * 4 + hc * 2);
        const h4 wB0 = *(const h4*)(wtr2 + (rB + 0) * 4 + hc * 2);
        const h4 wB1 = *(const h4*)(wtr2 + (rB + 1) * 4 + hc * 2);
        const h4 wB2 = *(const h4*)(wtr2 + (rB + 2) * 4 + hc * 2);
        h4 yA[4], yB[4];
        #pragma unroll
        for (int j = 0; j < 4; ++j) {
            yA[j] = hc ? __builtin_shufflevector(yAv[j], yAv[j], 4, 5, 6, 7)
                       : __builtin_shufflevector(yAv[j], yAv[j], 0, 1, 2, 3);
            yB[j] = hc ? __builtin_shufflevector(yBv[j], yBv[j], 4, 5, 6, 7)
                       : __builtin_shufflevector(yBv[j], yBv[j], 0, 1, 2, 3);
        }
        acc[0] = hdot4(wB1, yB[0], hdot4(wA1, yA[0], acc[0]));
        acc[1] = hdot4(wB0, yB[1], hdot4(wB2, yB[0],
                 hdot4(wA0, yA[1], hdot4(wA2, yA[0], acc[1]))));
        acc[2] = hdot4(wB1, yB[1], hdot4(wA1, yA[1], acc[2]));
        acc[3] = hdot4(wB0, yB[2], hdot4(wB2, yB[1],
                 hdot4(wA0, yA[2], hdot4(wA2, yA[1], acc[3]))));
        acc[4] = hdot4(wB1, yB[2], hdot4(wA1, yA[2], acc[4]));
        acc[5] = hdot4(wB0, yB[3], hdot4(wB2, yB[2],
                 hdot4(wA0, yA[3], hdot4(wA2, yA[2], acc[5]))));
        acc[6] = hdot4(wB1, yB[3], hdot4(wA1, yA[3], acc[6]));
        acc[7] = hdot4(wB2, yB[3], hdot4(wA2, yA[3], acc[7]));
    }
    if (idw >= 0) {
        float* og = out + (size_t)idw * 896 + g * 64 + oi * 8;
        *(float4*)(og)     = make_float4(fmaxf(acc[0]+bias,0.f), fmaxf(acc[1]+bias,0.f),
                                         fmaxf(acc[2]+bias,0.f), fmaxf(acc[3]+bias,0.f));
        *(float4*)(og + 4) = make_float4(fmaxf(acc[4]+bias,0.f), fmaxf(acc[5]+bias,0.f),
                                         fmaxf(acc[6]+bias,0.f), fmaxf(acc[7]+bias,0.f));
    }
}

extern "C" void kernel_launch(void* const* d_in, const int* in_sizes, int n_in,
                              void* d_out, int out_size, void* d_ws, size_t ws_size,
                              hipStream_t stream) {
    const float* x            = (const float*)d_in[0];
    const int*   keys         = (const int*)d_in[1];
    const float* conv_mask    = (const float*)d_in[2];
    const float* enc_conv_w   = (const float*)d_in[3];
    const float* enc_dense_w  = (const float*)d_in[4];
    const float* enc_dense_b  = (const float*)d_in[5];
    const float* dec_dense_w  = (const float*)d_in[6];
    const float* dec_dense_b  = (const float*)d_in[7];
    const float* dec_tconv_w  = (const float*)d_in[8];
    const float* dec_tconv_b  = (const float*)d_in[9];
    float* out = (float*)d_out;

    const int N = in_sizes[0] / (NG * 64);                   // 4096
    const int CHUNKS = (N + NE * (NW - 1)) / NW + 1;         // 144
    int* sorted = (int*)d_ws;

    bin_kernel<<<1, 1024, 0, stream>>>(keys, N, CHUNKS * NW, sorted);
    ae_main<<<CHUNKS * NG, 256, 0, stream>>>(
        x, keys, conv_mask, enc_conv_w, enc_dense_w, enc_dense_b,
        dec_dense_w, dec_dense_b, dec_tconv_w, dec_tconv_b, sorted, out);
}